// Round 17
// baseline (93.789 us; speedup 1.0000x reference)
//
#include <hip/hip_runtime.h>
#include <stdint.h>

// BiaffineSpanHead: B=4, S=1024, IN=1024, H=256, C=8
// out[b,s,e,c] = sum_{h,g} Hs[b,s,h] U[h,c,g] He[b,e,g] + linS[b,s,c] + linE[b,e,c] + Wb[c]
//
// R17 = R16 with the compile fix: nontemporal stores use ext_vector_type
// (u16x4), not HIP's ushort4 class. All intermediate writes (Hboth, Ut, Tbf)
// + K3 output are nt.

#define BDIM 256

typedef float f32x4 __attribute__((ext_vector_type(4)));
typedef __bf16 bf16x8 __attribute__((ext_vector_type(8)));
typedef unsigned short u16x4 __attribute__((ext_vector_type(4)));
typedef unsigned int u32;
typedef unsigned short u16;
typedef const __attribute__((address_space(1))) u32* gas_ptr;
typedef __attribute__((address_space(3))) u32* las_ptr;

static __device__ __forceinline__ void load_lds16(const void* g, void* l) {
  __builtin_amdgcn_global_load_lds((gas_ptr)g, (las_ptr)l, 16, 0, 0);
}

static __device__ __forceinline__ u16 f32_to_bf16(float f) {
  union { float f; u32 u; } v; v.f = f;
  u32 r = v.u + 0x7FFFu + ((v.u >> 16) & 1u);
  return (u16)(r >> 16);
}
static __device__ __forceinline__ u32 pack_bf16(float lo, float hi) {
  return (u32)f32_to_bf16(lo) | ((u32)f32_to_bf16(hi) << 16);
}
static __device__ __forceinline__ float bf16lo_to_f32(u32 u) {
  union { u32 u; float f; } v; v.u = u << 16;
  return v.f;
}
static __device__ __forceinline__ float bf16hi_to_f32(u32 u) {
  union { u32 u; float f; } v; v.u = u & 0xFFFF0000u;
  return v.f;
}
static __device__ __forceinline__ void nt_store_u16(u16* p, u16 v) {
  __builtin_nontemporal_store(v, p);
}

// stage a 32-row x 64-col bf16 stripe via global_load_lds; LDS slot sl of row
// r holds k-group sl ^ (r&7) (T2 swizzle via pre-swizzled source).
static __device__ __forceinline__ void stage32(u16* lds, int dst, const u16* src,
                                               int srow, int ld, int kcol, int tid) {
  const int r = tid >> 3;        // 0..31
  const int sl = tid & 7;
  load_lds16(src + (size_t)(srow + r) * ld + kcol + ((sl ^ (r & 7)) << 3),
             &lds[dst + tid * 8]);
}

// same stripe+layout, but source is f32: reg-stage (load f32x8, cvt, one 16B
// ds_write). Bit-identical LDS image to stage32.
static __device__ __forceinline__ void stage32_f32(u16* lds, int dst, const float* src,
                                                   int srow, int ld, int kcol, int tid) {
  const int r = tid >> 3;
  const int sl = tid & 7;
  const float* p = src + (size_t)(srow + r) * ld + kcol + ((sl ^ (r & 7)) << 3);
  const float4 v0 = *reinterpret_cast<const float4*>(p);
  const float4 v1 = *reinterpret_cast<const float4*>(p + 4);
  uint4 w;
  w.x = pack_bf16(v0.x, v0.y);
  w.y = pack_bf16(v0.z, v0.w);
  w.z = pack_bf16(v1.x, v1.y);
  w.w = pack_bf16(v1.z, v1.w);
  *reinterpret_cast<uint4*>(&lds[dst + tid * 8]) = w;
}

// read an 8-elem bf16 fragment from a swizzled 64-col row
static __device__ __forceinline__ bf16x8 rd64(const u16* lds, int base, int row, int kslot) {
  return *reinterpret_cast<const bf16x8*>(&lds[base + row * 64 + ((kslot ^ (row & 7)) << 3)]);
}

// ---------------------------------------------------------------------------
// k1p: blocks <512: Hboth = X @ [sw;ew]^T + bias, 64x64 tile, BK=64,
//      A/B reg-staged f32->bf16. blocks >=512: Ut cast.  (R9/R12-proven)
// ---------------------------------------------------------------------------
__global__ __launch_bounds__(BDIM, 4)
void k1p(const float* __restrict__ seq,   // [4096][1024]
         const float* __restrict__ sw,    // [256][1024]
         const float* __restrict__ ew,    // [256][1024]
         const float* __restrict__ U,     // [256][2048]
         const float* __restrict__ sb,
         const float* __restrict__ eb,
         u16* __restrict__ Hboth,         // [4096][512]
         u16* __restrict__ Ut)            // [2048][256]
{
  const int tid = threadIdx.x;
  const int bid = blockIdx.x;

  if (bid >= 512) {
    const int i = (bid - 512) * 1024 + tid * 4;   // i = n*256 + h
    const int n = i >> 8;
    const int h = i & 255;
    u16x4 o;
    o[0] = f32_to_bf16(U[(size_t)(h + 0) * 2048 + n]);
    o[1] = f32_to_bf16(U[(size_t)(h + 1) * 2048 + n]);
    o[2] = f32_to_bf16(U[(size_t)(h + 2) * 2048 + n]);
    o[3] = f32_to_bf16(U[(size_t)(h + 3) * 2048 + n]);
    __builtin_nontemporal_store(o, reinterpret_cast<u16x4*>(Ut + i));
    return;
  }

  __shared__ u16 lds[2 * 4096];   // A [64][64] @0, B [64][64] @4096

  const int lane = tid & 63;
  const int wv   = tid >> 6;     // 0..3
  const int wr   = wv >> 1;      // 0..1 (32-row half)
  const int wq   = wv & 1;       // 0..1 (32-col half)
  const int rA   = lane & 15;
  const int kq   = lane >> 4;    // 0..3

  int id = bid;                                     // 0..511
  id = (id & 7) * 64 + (id >> 3);                   // bijective XCD swizzle
  const int n0 = (id & 7) * 64;
  const int m0 = (id >> 3) * 64;

  const float* wsrc = (n0 < 256) ? (sw + (size_t)n0 * 1024)
                                 : (ew + (size_t)(n0 - 256) * 1024);

  f32x4 acc[2][2];
#pragma unroll
  for (int i = 0; i < 2; ++i)
#pragma unroll
    for (int j = 0; j < 2; ++j) acc[i][j] = (f32x4)0.f;

#pragma unroll 1
  for (int kt = 0; kt < 1024; kt += 64) {
    stage32_f32(lds, 0,           seq,  m0,      1024, kt, tid);
    stage32_f32(lds, 2048,        seq,  m0 + 32, 1024, kt, tid);
    stage32_f32(lds, 4096,        wsrc, 0,       1024, kt, tid);
    stage32_f32(lds, 4096 + 2048, wsrc, 32,      1024, kt, tid);
    __syncthreads();

    bf16x8 aF[2][2], bF[2][2];
#pragma unroll
    for (int mi = 0; mi < 2; ++mi)
#pragma unroll
      for (int ks = 0; ks < 2; ++ks)
        aF[mi][ks] = rd64(lds, 0, wr * 32 + mi * 16 + rA, (ks << 2) | kq);
#pragma unroll
    for (int ni = 0; ni < 2; ++ni)
#pragma unroll
      for (int ks = 0; ks < 2; ++ks)
        bF[ni][ks] = rd64(lds, 4096, wq * 32 + ni * 16 + rA, (ks << 2) | kq);
#pragma unroll
    for (int mi = 0; mi < 2; ++mi)
#pragma unroll
      for (int ni = 0; ni < 2; ++ni)
#pragma unroll
        for (int ks = 0; ks < 2; ++ks)
          acc[mi][ni] = __builtin_amdgcn_mfma_f32_16x16x32_bf16(
              aF[mi][ks], bF[ni][ks], acc[mi][ni], 0, 0, 0);
    __syncthreads();
  }

#pragma unroll
  for (int mi = 0; mi < 2; ++mi) {
#pragma unroll
    for (int ni = 0; ni < 2; ++ni) {
      const int n = n0 + wq * 32 + ni * 16 + rA;
      const float bn = (n < 256) ? sb[n] : eb[n - 256];
      const int mr = m0 + wr * 32 + mi * 16 + kq * 4;
#pragma unroll
      for (int r = 0; r < 4; ++r)
        nt_store_u16(&Hboth[(size_t)(mr + r) * 512 + n],
                     f32_to_bf16(acc[mi][ni][r] + bn));
    }
  }
}

// ---------------------------------------------------------------------------
// k2lin (R12-proven): blocks 0..511 = K2 (128^2, BK=64, swizzled, single
// buffer); blocks 512..639 = lin.  Tbf stores nt.
// ---------------------------------------------------------------------------
__global__ __launch_bounds__(BDIM, 2)
void k2lin(const u16* __restrict__ Hboth,
           const u16* __restrict__ Utbf,
           u16* __restrict__ Tbf,
           const float* __restrict__ Ww,
           const float* __restrict__ Wb,
           float* __restrict__ linS,
           float* __restrict__ linE)
{
  const int bid = blockIdx.x;
  const int tid = threadIdx.x;

  if (bid >= 512) {
    const int idx = (bid - 512) * BDIM + tid;   // 0..32767
    const int m = idx >> 3;
    const int c = idx & 7;
    const uint4* hs4 = reinterpret_cast<const uint4*>(Hboth + (size_t)m * 512);
    const uint4* he4 = reinterpret_cast<const uint4*>(Hboth + (size_t)m * 512 + 256);
    const float* wsp = Ww + c * 512;
    const float* wep = wsp + 256;
    float s1 = 0.f, s2 = 0.f;
#pragma unroll 4
    for (int t = 0; t < 32; ++t) {
      const uint4 a = hs4[t];
      const uint4 b = he4[t];
      const u32 aw[4] = {a.x, a.y, a.z, a.w};
      const u32 bw[4] = {b.x, b.y, b.z, b.w};
#pragma unroll
      for (int q = 0; q < 4; ++q) {
        const int h = t * 8 + q * 2;
        s1 += bf16lo_to_f32(aw[q]) * wsp[h] + bf16hi_to_f32(aw[q]) * wsp[h + 1];
        s2 += bf16lo_to_f32(bw[q]) * wep[h] + bf16hi_to_f32(bw[q]) * wep[h + 1];
      }
    }
    linS[idx] = s1;
    linE[idx] = s2 + Wb[c];
    return;
  }

  __shared__ u16 lds[2 * 8192];   // A [128][64] @0, B [128][64] @8192

  int id = bid;
  id = (id & 7) * 64 + (id >> 3);
  const int n0 = (id & 15) * 128;
  const int m0 = (id >> 4) * 128;

  const int lane = tid & 63;
  const int wv   = tid >> 6;
  const int wr   = wv >> 1;
  const int wc   = wv & 1;
  const int rA   = lane & 15;
  const int kq   = lane >> 4;

  f32x4 acc[4][4];
#pragma unroll
  for (int i = 0; i < 4; ++i)
#pragma unroll
    for (int j = 0; j < 4; ++j) acc[i][j] = (f32x4)0.f;

#pragma unroll 1
  for (int kt = 0; kt < 256; kt += 64) {
#pragma unroll
    for (int h = 0; h < 4; ++h)
      stage32(lds, h * 2048, Hboth, m0 + h * 32, 512, kt, tid);
#pragma unroll
    for (int h = 0; h < 4; ++h)
      stage32(lds, 8192 + h * 2048, Utbf, n0 + h * 32, 256, kt, tid);
    __syncthreads();

    bf16x8 aF[4][2], bF[4][2];
#pragma unroll
    for (int mi = 0; mi < 4; ++mi)
#pragma unroll
      for (int ks = 0; ks < 2; ++ks)
        aF[mi][ks] = rd64(lds, 0, wr * 64 + mi * 16 + rA, (ks << 2) | kq);
#pragma unroll
    for (int ni = 0; ni < 4; ++ni)
#pragma unroll
      for (int ks = 0; ks < 2; ++ks)
        bF[ni][ks] = rd64(lds, 8192, wc * 64 + ni * 16 + rA, (ks << 2) | kq);
#pragma unroll
    for (int mi = 0; mi < 4; ++mi)
#pragma unroll
      for (int ni = 0; ni < 4; ++ni)
#pragma unroll
        for (int ks = 0; ks < 2; ++ks)
          acc[mi][ni] = __builtin_amdgcn_mfma_f32_16x16x32_bf16(
              aF[mi][ks], bF[ni][ks], acc[mi][ni], 0, 0, 0);
    __syncthreads();
  }

#pragma unroll
  for (int mi = 0; mi < 4; ++mi) {
#pragma unroll
    for (int ni = 0; ni < 4; ++ni) {
      const int mBase = m0 + wr * 64 + mi * 16 + kq * 4;
      const int n = n0 + wc * 64 + ni * 16 + rA;
#pragma unroll
      for (int r = 0; r < 4; ++r)
        nt_store_u16(&Tbf[(size_t)(mBase + r) * 2048 + n],
                     f32_to_bf16(acc[mi][ni][r]));
    }
  }
}

// ---------------------------------------------------------------------------
// K3 (R15-proven, verbatim): 128x128, BK=64 dbuf, counted vmcnt, z pinned to
// XCD pair, nt output stores.
// ---------------------------------------------------------------------------
#define K3STAGE(buf, t) do {                                                   \
    _Pragma("unroll")                                                          \
    for (int h = 0; h < 4; ++h)                                                \
      stage32(lds, (buf) * 16384 + h * 2048, Ag, m0 + h * 32, 256, (t) * 64, tid); \
    _Pragma("unroll")                                                          \
    for (int h = 0; h < 4; ++h)                                                \
      stage32(lds, (buf) * 16384 + 8192 + h * 2048, Bgz, n0 + h * 32, 512, (t) * 64, tid); \
  } while (0)

__global__ __launch_bounds__(BDIM, 2)
void gemm128_biaff(const u16* __restrict__ Tall,
                   const u16* __restrict__ Bg,
                   float* __restrict__ Out,
                   const float* __restrict__ linSall,
                   const float* __restrict__ linEall)
{
  __shared__ u16 lds[4 * 8192];

  const int tid  = threadIdx.x;
  const int lane = tid & 63;
  const int wv   = tid >> 6;       // 0..3
  const int wr   = wv >> 1;        // 0..1
  const int wc   = wv & 1;         // 0..1
  const int rA   = lane & 15;
  const int kq   = lane >> 4;      // 0..3

  const int bid  = blockIdx.x;
  const int z    = (bid & 7) >> 1;
  const int tile = ((bid >> 3) << 1) | (bid & 1);
  const int n0 = (tile & 7) * 128;
  const int m0 = (tile >> 3) * 128;

  const u16* Ag  = Tall + (size_t)z * (8192 * 256);
  const u16* Bgz = Bg   + (size_t)z * (1024 * 512);

  f32x4 acc[4][4];
#pragma unroll
  for (int i = 0; i < 4; ++i)
#pragma unroll
    for (int j = 0; j < 4; ++j) acc[i][j] = (f32x4)0.f;

  const float* lS = linSall + (size_t)z * 8192;
  float4 ls4[4];
#pragma unroll
  for (int mi = 0; mi < 4; ++mi)
    ls4[mi] = *reinterpret_cast<const float4*>(lS + m0 + wr * 64 + mi * 16 + kq * 4);

  K3STAGE(0, 0);

#pragma unroll
  for (int t = 0; t < 4; ++t) {
    const int cur = t & 1;
    if (t < 3) {
      K3STAGE(cur ^ 1, t + 1);
      asm volatile("s_waitcnt vmcnt(8)" ::: "memory");
    } else {
      asm volatile("s_waitcnt vmcnt(0)" ::: "memory");
    }
    __builtin_amdgcn_sched_barrier(0);
    __builtin_amdgcn_s_barrier();

    bf16x8 aF[4][2], bF[4][2];
#pragma unroll
    for (int mi = 0; mi < 4; ++mi)
#pragma unroll
      for (int ks = 0; ks < 2; ++ks)
        aF[mi][ks] = rd64(lds, cur * 16384, wr * 64 + mi * 16 + rA, (ks << 2) | kq);
#pragma unroll
    for (int ni = 0; ni < 4; ++ni)
#pragma unroll
      for (int ks = 0; ks < 2; ++ks)
        bF[ni][ks] = rd64(lds, cur * 16384 + 8192, wc * 64 + ni * 16 + rA, (ks << 2) | kq);
#pragma unroll
    for (int mi = 0; mi < 4; ++mi)
#pragma unroll
      for (int ni = 0; ni < 4; ++ni)
#pragma unroll
        for (int ks = 0; ks < 2; ++ks)
          acc[mi][ni] = __builtin_amdgcn_mfma_f32_16x16x32_bf16(
              aF[mi][ks], bF[ni][ks], acc[mi][ni], 0, 0, 0);

    __builtin_amdgcn_sched_barrier(0);
    __builtin_amdgcn_s_barrier();
  }

  float* OutZ = Out + (size_t)z * 8388608;
  const float* lE = linEall + (size_t)z * 8192;
#pragma unroll
  for (int mi = 0; mi < 4; ++mi) {
#pragma unroll
    for (int ni = 0; ni < 4; ++ni) {
      const int mBase = m0 + wr * 64 + mi * 16 + kq * 4;   // = s*8 + c0
      const int e = n0 + wc * 64 + ni * 16 + rA;
      const int s = mBase >> 3;
      const int c0 = mBase & 7;
      const float4 le4 = *reinterpret_cast<const float4*>(lE + (e << 3) + c0);
      f32x4 o;
      o[0] = acc[mi][ni][0] + ls4[mi].x + le4.x;
      o[1] = acc[mi][ni][1] + ls4[mi].y + le4.y;
      o[2] = acc[mi][ni][2] + ls4[mi].z + le4.z;
      o[3] = acc[mi][ni][3] + ls4[mi].w + le4.w;
      __builtin_nontemporal_store(
          o, reinterpret_cast<f32x4*>(OutZ + ((size_t)s << 13) + ((size_t)e << 3) + c0));
    }
  }
}

// ---------------------------------------------------------------------------
extern "C" void kernel_launch(void* const* d_in, const int* in_sizes, int n_in,
                              void* d_out, int out_size, void* d_ws, size_t ws_size,
                              hipStream_t stream)
{
  const float* seq = (const float*)d_in[0];
  const float* U   = (const float*)d_in[1];
  const float* Ww  = (const float*)d_in[2];
  const float* Wb  = (const float*)d_in[3];
  const float* sw  = (const float*)d_in[4];
  const float* sb  = (const float*)d_in[5];
  const float* ew  = (const float*)d_in[6];
  const float* eb  = (const float*)d_in[7];
  float* out = (float*)d_out;

  u16* Utbf  = (u16*)d_ws;                 // 524288  [2048][256]
  u16* Hboth = Utbf + 524288;              // 2097152 [4096][512]
  u16* Tbf   = Hboth + 2097152;            // 8388608 [4096][2048]
  float* linS = (float*)(Tbf + 8388608);   // 32768
  float* linE = linS + 32768;              // 32768

  // K1 + Ut-cast
  k1p<<<1024, BDIM, 0, stream>>>(seq, sw, ew, U, sb, eb, Hboth, Utbf);

  // K2 (single-buffer BK=64) + lin
  k2lin<<<640, BDIM, 0, stream>>>(Hboth, Utbf, Tbf, Ww, Wb, linS, linE);

  // K3: out[b] = T[b] @ He[b]^T + lin  (z pinned to XCD pair, nt stores)
  gemm128_biaff<<<2048, BDIM, 0, stream>>>(
      Tbf, Hboth + 256, out, linS, linE);
}

// Round 18
// 78.701 us; speedup vs baseline: 1.1917x; 1.1917x over previous
//
#include <hip/hip_runtime.h>
#include <stdint.h>

// BiaffineSpanHead: B=4, S=1024, IN=1024, H=256, C=8
// out[b,s,e,c] = sum_{h,g} Hs[b,s,h] U[h,c,g] He[b,e,g] + linS[b,s,c] + linE[b,e,c] + Wb[c]
//
// R18 = R15 verbatim (measured best, 78.9us). R17's nt-on-intermediates
// reverted: nt is only safe on wide aligned f32x4 streams (K3 output);
// scalar u16 epilogue stores need L2 write-combining.

#define BDIM 256

typedef float f32x4 __attribute__((ext_vector_type(4)));
typedef __bf16 bf16x8 __attribute__((ext_vector_type(8)));
typedef unsigned int u32;
typedef unsigned short u16;
typedef const __attribute__((address_space(1))) u32* gas_ptr;
typedef __attribute__((address_space(3))) u32* las_ptr;

static __device__ __forceinline__ void load_lds16(const void* g, void* l) {
  __builtin_amdgcn_global_load_lds((gas_ptr)g, (las_ptr)l, 16, 0, 0);
}

static __device__ __forceinline__ u16 f32_to_bf16(float f) {
  union { float f; u32 u; } v; v.f = f;
  u32 r = v.u + 0x7FFFu + ((v.u >> 16) & 1u);
  return (u16)(r >> 16);
}
static __device__ __forceinline__ u32 pack_bf16(float lo, float hi) {
  return (u32)f32_to_bf16(lo) | ((u32)f32_to_bf16(hi) << 16);
}
static __device__ __forceinline__ float bf16lo_to_f32(u32 u) {
  union { u32 u; float f; } v; v.u = u << 16;
  return v.f;
}
static __device__ __forceinline__ float bf16hi_to_f32(u32 u) {
  union { u32 u; float f; } v; v.u = u & 0xFFFF0000u;
  return v.f;
}

// stage a 32-row x 64-col bf16 stripe via global_load_lds; LDS slot sl of row
// r holds k-group sl ^ (r&7) (T2 swizzle via pre-swizzled source).
static __device__ __forceinline__ void stage32(u16* lds, int dst, const u16* src,
                                               int srow, int ld, int kcol, int tid) {
  const int r = tid >> 3;        // 0..31
  const int sl = tid & 7;
  load_lds16(src + (size_t)(srow + r) * ld + kcol + ((sl ^ (r & 7)) << 3),
             &lds[dst + tid * 8]);
}

// same stripe+layout, but source is f32: reg-stage (load f32x8, cvt, one 16B
// ds_write). Bit-identical LDS image to stage32.
static __device__ __forceinline__ void stage32_f32(u16* lds, int dst, const float* src,
                                                   int srow, int ld, int kcol, int tid) {
  const int r = tid >> 3;
  const int sl = tid & 7;
  const float* p = src + (size_t)(srow + r) * ld + kcol + ((sl ^ (r & 7)) << 3);
  const float4 v0 = *reinterpret_cast<const float4*>(p);
  const float4 v1 = *reinterpret_cast<const float4*>(p + 4);
  uint4 w;
  w.x = pack_bf16(v0.x, v0.y);
  w.y = pack_bf16(v0.z, v0.w);
  w.z = pack_bf16(v1.x, v1.y);
  w.w = pack_bf16(v1.z, v1.w);
  *reinterpret_cast<uint4*>(&lds[dst + tid * 8]) = w;
}

// read an 8-elem bf16 fragment from a swizzled 64-col row
static __device__ __forceinline__ bf16x8 rd64(const u16* lds, int base, int row, int kslot) {
  return *reinterpret_cast<const bf16x8*>(&lds[base + row * 64 + ((kslot ^ (row & 7)) << 3)]);
}

// ---------------------------------------------------------------------------
// k1p: blocks <512: Hboth = X @ [sw;ew]^T + bias, 64x64 tile, BK=64,
//      A/B reg-staged f32->bf16. blocks >=512: Ut cast.  (R9/R12-proven)
// ---------------------------------------------------------------------------
__global__ __launch_bounds__(BDIM, 4)
void k1p(const float* __restrict__ seq,   // [4096][1024]
         const float* __restrict__ sw,    // [256][1024]
         const float* __restrict__ ew,    // [256][1024]
         const float* __restrict__ U,     // [256][2048]
         const float* __restrict__ sb,
         const float* __restrict__ eb,
         u16* __restrict__ Hboth,         // [4096][512]
         u16* __restrict__ Ut)            // [2048][256]
{
  const int tid = threadIdx.x;
  const int bid = blockIdx.x;

  if (bid >= 512) {
    const int i = (bid - 512) * 1024 + tid * 4;   // i = n*256 + h
    const int n = i >> 8;
    const int h = i & 255;
    ushort4 o;
    o.x = f32_to_bf16(U[(size_t)(h + 0) * 2048 + n]);
    o.y = f32_to_bf16(U[(size_t)(h + 1) * 2048 + n]);
    o.z = f32_to_bf16(U[(size_t)(h + 2) * 2048 + n]);
    o.w = f32_to_bf16(U[(size_t)(h + 3) * 2048 + n]);
    *reinterpret_cast<ushort4*>(Ut + i) = o;
    return;
  }

  __shared__ u16 lds[2 * 4096];   // A [64][64] @0, B [64][64] @4096

  const int lane = tid & 63;
  const int wv   = tid >> 6;     // 0..3
  const int wr   = wv >> 1;      // 0..1 (32-row half)
  const int wq   = wv & 1;       // 0..1 (32-col half)
  const int rA   = lane & 15;
  const int kq   = lane >> 4;    // 0..3

  int id = bid;                                     // 0..511
  id = (id & 7) * 64 + (id >> 3);                   // bijective XCD swizzle
  const int n0 = (id & 7) * 64;
  const int m0 = (id >> 3) * 64;

  const float* wsrc = (n0 < 256) ? (sw + (size_t)n0 * 1024)
                                 : (ew + (size_t)(n0 - 256) * 1024);

  f32x4 acc[2][2];
#pragma unroll
  for (int i = 0; i < 2; ++i)
#pragma unroll
    for (int j = 0; j < 2; ++j) acc[i][j] = (f32x4)0.f;

#pragma unroll 1
  for (int kt = 0; kt < 1024; kt += 64) {
    stage32_f32(lds, 0,           seq,  m0,      1024, kt, tid);
    stage32_f32(lds, 2048,        seq,  m0 + 32, 1024, kt, tid);
    stage32_f32(lds, 4096,        wsrc, 0,       1024, kt, tid);
    stage32_f32(lds, 4096 + 2048, wsrc, 32,      1024, kt, tid);
    __syncthreads();

    bf16x8 aF[2][2], bF[2][2];
#pragma unroll
    for (int mi = 0; mi < 2; ++mi)
#pragma unroll
      for (int ks = 0; ks < 2; ++ks)
        aF[mi][ks] = rd64(lds, 0, wr * 32 + mi * 16 + rA, (ks << 2) | kq);
#pragma unroll
    for (int ni = 0; ni < 2; ++ni)
#pragma unroll
      for (int ks = 0; ks < 2; ++ks)
        bF[ni][ks] = rd64(lds, 4096, wq * 32 + ni * 16 + rA, (ks << 2) | kq);
#pragma unroll
    for (int mi = 0; mi < 2; ++mi)
#pragma unroll
      for (int ni = 0; ni < 2; ++ni)
#pragma unroll
        for (int ks = 0; ks < 2; ++ks)
          acc[mi][ni] = __builtin_amdgcn_mfma_f32_16x16x32_bf16(
              aF[mi][ks], bF[ni][ks], acc[mi][ni], 0, 0, 0);
    __syncthreads();
  }

#pragma unroll
  for (int mi = 0; mi < 2; ++mi) {
#pragma unroll
    for (int ni = 0; ni < 2; ++ni) {
      const int n = n0 + wq * 32 + ni * 16 + rA;
      const float bn = (n < 256) ? sb[n] : eb[n - 256];
      const int mr = m0 + wr * 32 + mi * 16 + kq * 4;
#pragma unroll
      for (int r = 0; r < 4; ++r)
        Hboth[(size_t)(mr + r) * 512 + n] = f32_to_bf16(acc[mi][ni][r] + bn);
    }
  }
}

// ---------------------------------------------------------------------------
// k2lin (R12-proven, verbatim): blocks 0..511 = K2 (128^2, BK=64, swizzled,
// single buffer); blocks 512..639 = lin.
// ---------------------------------------------------------------------------
__global__ __launch_bounds__(BDIM, 2)
void k2lin(const u16* __restrict__ Hboth,
           const u16* __restrict__ Utbf,
           u16* __restrict__ Tbf,
           const float* __restrict__ Ww,
           const float* __restrict__ Wb,
           float* __restrict__ linS,
           float* __restrict__ linE)
{
  const int bid = blockIdx.x;
  const int tid = threadIdx.x;

  if (bid >= 512) {
    const int idx = (bid - 512) * BDIM + tid;   // 0..32767
    const int m = idx >> 3;
    const int c = idx & 7;
    const uint4* hs4 = reinterpret_cast<const uint4*>(Hboth + (size_t)m * 512);
    const uint4* he4 = reinterpret_cast<const uint4*>(Hboth + (size_t)m * 512 + 256);
    const float* wsp = Ww + c * 512;
    const float* wep = wsp + 256;
    float s1 = 0.f, s2 = 0.f;
#pragma unroll 4
    for (int t = 0; t < 32; ++t) {
      const uint4 a = hs4[t];
      const uint4 b = he4[t];
      const u32 aw[4] = {a.x, a.y, a.z, a.w};
      const u32 bw[4] = {b.x, b.y, b.z, b.w};
#pragma unroll
      for (int q = 0; q < 4; ++q) {
        const int h = t * 8 + q * 2;
        s1 += bf16lo_to_f32(aw[q]) * wsp[h] + bf16hi_to_f32(aw[q]) * wsp[h + 1];
        s2 += bf16lo_to_f32(bw[q]) * wep[h] + bf16hi_to_f32(bw[q]) * wep[h + 1];
      }
    }
    linS[idx] = s1;
    linE[idx] = s2 + Wb[c];
    return;
  }

  __shared__ u16 lds[2 * 8192];   // A [128][64] @0, B [128][64] @8192

  int id = bid;
  id = (id & 7) * 64 + (id >> 3);
  const int n0 = (id & 15) * 128;
  const int m0 = (id >> 4) * 128;

  const int lane = tid & 63;
  const int wv   = tid >> 6;
  const int wr   = wv >> 1;
  const int wc   = wv & 1;
  const int rA   = lane & 15;
  const int kq   = lane >> 4;

  f32x4 acc[4][4];
#pragma unroll
  for (int i = 0; i < 4; ++i)
#pragma unroll
    for (int j = 0; j < 4; ++j) acc[i][j] = (f32x4)0.f;

#pragma unroll 1
  for (int kt = 0; kt < 256; kt += 64) {
#pragma unroll
    for (int h = 0; h < 4; ++h)
      stage32(lds, h * 2048, Hboth, m0 + h * 32, 512, kt, tid);
#pragma unroll
    for (int h = 0; h < 4; ++h)
      stage32(lds, 8192 + h * 2048, Utbf, n0 + h * 32, 256, kt, tid);
    __syncthreads();

    bf16x8 aF[4][2], bF[4][2];
#pragma unroll
    for (int mi = 0; mi < 4; ++mi)
#pragma unroll
      for (int ks = 0; ks < 2; ++ks)
        aF[mi][ks] = rd64(lds, 0, wr * 64 + mi * 16 + rA, (ks << 2) | kq);
#pragma unroll
    for (int ni = 0; ni < 4; ++ni)
#pragma unroll
      for (int ks = 0; ks < 2; ++ks)
        bF[ni][ks] = rd64(lds, 8192, wc * 64 + ni * 16 + rA, (ks << 2) | kq);
#pragma unroll
    for (int mi = 0; mi < 4; ++mi)
#pragma unroll
      for (int ni = 0; ni < 4; ++ni)
#pragma unroll
        for (int ks = 0; ks < 2; ++ks)
          acc[mi][ni] = __builtin_amdgcn_mfma_f32_16x16x32_bf16(
              aF[mi][ks], bF[ni][ks], acc[mi][ni], 0, 0, 0);
    __syncthreads();
  }

#pragma unroll
  for (int mi = 0; mi < 4; ++mi) {
#pragma unroll
    for (int ni = 0; ni < 4; ++ni) {
      const int mBase = m0 + wr * 64 + mi * 16 + kq * 4;
      const int n = n0 + wc * 64 + ni * 16 + rA;
#pragma unroll
      for (int r = 0; r < 4; ++r)
        Tbf[(size_t)(mBase + r) * 2048 + n] = f32_to_bf16(acc[mi][ni][r]);
    }
  }
}

// ---------------------------------------------------------------------------
// K3 (R15-proven, verbatim): 128x128, BK=64 dbuf, counted vmcnt, z pinned to
// XCD pair, nt output stores (wide f32x4 only).
// ---------------------------------------------------------------------------
#define K3STAGE(buf, t) do {                                                   \
    _Pragma("unroll")                                                          \
    for (int h = 0; h < 4; ++h)                                                \
      stage32(lds, (buf) * 16384 + h * 2048, Ag, m0 + h * 32, 256, (t) * 64, tid); \
    _Pragma("unroll")                                                          \
    for (int h = 0; h < 4; ++h)                                                \
      stage32(lds, (buf) * 16384 + 8192 + h * 2048, Bgz, n0 + h * 32, 512, (t) * 64, tid); \
  } while (0)

__global__ __launch_bounds__(BDIM, 2)
void gemm128_biaff(const u16* __restrict__ Tall,
                   const u16* __restrict__ Bg,
                   float* __restrict__ Out,
                   const float* __restrict__ linSall,
                   const float* __restrict__ linEall)
{
  __shared__ u16 lds[4 * 8192];

  const int tid  = threadIdx.x;
  const int lane = tid & 63;
  const int wv   = tid >> 6;       // 0..3
  const int wr   = wv >> 1;        // 0..1
  const int wc   = wv & 1;         // 0..1
  const int rA   = lane & 15;
  const int kq   = lane >> 4;      // 0..3

  const int bid  = blockIdx.x;
  const int z    = (bid & 7) >> 1;
  const int tile = ((bid >> 3) << 1) | (bid & 1);
  const int n0 = (tile & 7) * 128;
  const int m0 = (tile >> 3) * 128;

  const u16* Ag  = Tall + (size_t)z * (8192 * 256);
  const u16* Bgz = Bg   + (size_t)z * (1024 * 512);

  f32x4 acc[4][4];
#pragma unroll
  for (int i = 0; i < 4; ++i)
#pragma unroll
    for (int j = 0; j < 4; ++j) acc[i][j] = (f32x4)0.f;

  const float* lS = linSall + (size_t)z * 8192;
  float4 ls4[4];
#pragma unroll
  for (int mi = 0; mi < 4; ++mi)
    ls4[mi] = *reinterpret_cast<const float4*>(lS + m0 + wr * 64 + mi * 16 + kq * 4);

  K3STAGE(0, 0);

#pragma unroll
  for (int t = 0; t < 4; ++t) {
    const int cur = t & 1;
    if (t < 3) {
      K3STAGE(cur ^ 1, t + 1);
      asm volatile("s_waitcnt vmcnt(8)" ::: "memory");
    } else {
      asm volatile("s_waitcnt vmcnt(0)" ::: "memory");
    }
    __builtin_amdgcn_sched_barrier(0);
    __builtin_amdgcn_s_barrier();

    bf16x8 aF[4][2], bF[4][2];
#pragma unroll
    for (int mi = 0; mi < 4; ++mi)
#pragma unroll
      for (int ks = 0; ks < 2; ++ks)
        aF[mi][ks] = rd64(lds, cur * 16384, wr * 64 + mi * 16 + rA, (ks << 2) | kq);
#pragma unroll
    for (int ni = 0; ni < 4; ++ni)
#pragma unroll
      for (int ks = 0; ks < 2; ++ks)
        bF[ni][ks] = rd64(lds, cur * 16384 + 8192, wc * 64 + ni * 16 + rA, (ks << 2) | kq);
#pragma unroll
    for (int mi = 0; mi < 4; ++mi)
#pragma unroll
      for (int ni = 0; ni < 4; ++ni)
#pragma unroll
        for (int ks = 0; ks < 2; ++ks)
          acc[mi][ni] = __builtin_amdgcn_mfma_f32_16x16x32_bf16(
              aF[mi][ks], bF[ni][ks], acc[mi][ni], 0, 0, 0);

    __builtin_amdgcn_sched_barrier(0);
    __builtin_amdgcn_s_barrier();
  }

  float* OutZ = Out + (size_t)z * 8388608;
  const float* lE = linEall + (size_t)z * 8192;
#pragma unroll
  for (int mi = 0; mi < 4; ++mi) {
#pragma unroll
    for (int ni = 0; ni < 4; ++ni) {
      const int mBase = m0 + wr * 64 + mi * 16 + kq * 4;   // = s*8 + c0
      const int e = n0 + wc * 64 + ni * 16 + rA;
      const int s = mBase >> 3;
      const int c0 = mBase & 7;
      const float4 le4 = *reinterpret_cast<const float4*>(lE + (e << 3) + c0);
      f32x4 o;
      o[0] = acc[mi][ni][0] + ls4[mi].x + le4.x;
      o[1] = acc[mi][ni][1] + ls4[mi].y + le4.y;
      o[2] = acc[mi][ni][2] + ls4[mi].z + le4.z;
      o[3] = acc[mi][ni][3] + ls4[mi].w + le4.w;
      __builtin_nontemporal_store(
          o, reinterpret_cast<f32x4*>(OutZ + ((size_t)s << 13) + ((size_t)e << 3) + c0));
    }
  }
}

// ---------------------------------------------------------------------------
extern "C" void kernel_launch(void* const* d_in, const int* in_sizes, int n_in,
                              void* d_out, int out_size, void* d_ws, size_t ws_size,
                              hipStream_t stream)
{
  const float* seq = (const float*)d_in[0];
  const float* U   = (const float*)d_in[1];
  const float* Ww  = (const float*)d_in[2];
  const float* Wb  = (const float*)d_in[3];
  const float* sw  = (const float*)d_in[4];
  const float* sb  = (const float*)d_in[5];
  const float* ew  = (const float*)d_in[6];
  const float* eb  = (const float*)d_in[7];
  float* out = (float*)d_out;

  u16* Utbf  = (u16*)d_ws;                 // 524288  [2048][256]
  u16* Hboth = Utbf + 524288;              // 2097152 [4096][512]
  u16* Tbf   = Hboth + 2097152;            // 8388608 [4096][2048]
  float* linS = (float*)(Tbf + 8388608);   // 32768
  float* linE = linS + 32768;              // 32768

  // K1 + Ut-cast
  k1p<<<1024, BDIM, 0, stream>>>(seq, sw, ew, U, sb, eb, Hboth, Utbf);

  // K2 (single-buffer BK=64) + lin
  k2lin<<<640, BDIM, 0, stream>>>(Hboth, Utbf, Tbf, Ww, Wb, linS, linE);

  // K3: out[b] = T[b] @ He[b]^T + lin  (z pinned to XCD pair, nt stores)
  gemm128_biaff<<<2048, BDIM, 0, stream>>>(
      Tbf, Hboth + 256, out, linS, linE);
}